// Round 5
// baseline (312.206 us; speedup 1.0000x reference)
//
#include <hip/hip_runtime.h>

typedef float f32x4 __attribute__((ext_vector_type(4)));
typedef float f32x16 __attribute__((ext_vector_type(16)));
typedef _Float16 half8 __attribute__((ext_vector_type(8)));
typedef _Float16 half2v __attribute__((ext_vector_type(2)));
typedef unsigned u32x4 __attribute__((ext_vector_type(4)));

__device__ __forceinline__ unsigned f2mono(float f) {
  unsigned u = __float_as_uint(f);
  return (u & 0x80000000u) ? ~u : (u | 0x80000000u);
}
__device__ __forceinline__ float mono2f(unsigned u) {
  return (u & 0x80000000u) ? __uint_as_float(u & 0x7fffffffu) : __uint_as_float(~u);
}
__device__ __forceinline__ float lrelu(float x) { return fmaxf(x, 0.2f * x); }
__device__ __forceinline__ unsigned pkrtz(float a, float b) {
  return __builtin_bit_cast(unsigned, __builtin_amdgcn_cvt_pkrtz(a, b));
}
__device__ __forceinline__ half8 ash8(u32x4 u) { return __builtin_bit_cast(half8, u); }

// ---------------- init: global_feats = mono(-1e9) ----------------
__global__ void sc_init(unsigned* __restrict__ gf, int total4) {
  int i = blockIdx.x * blockDim.x + threadIdx.x;
  if (i < total4) {
    unsigned m = f2mono(-1.0e9f);
    ((uint4*)gf)[i] = make_uint4(m, m, m, m);
  }
}

// ---- fused: gather + L1(fp16 x-split MFMA) + L2(fp16 MFMA) + running seg-max ----
// Wave owns one contiguous chunk. Running per-feature max in regs; flush on batch
// transition. Interior batches -> plain store; boundary -> atomicMax.
// No launch_bounds: let the allocator pick (R3 showed a forced cap => spill disaster).
__global__ void sc_main(
    const float* __restrict__ muons, const int* __restrict__ bidx,
    const float* __restrict__ cond, const float* __restrict__ W1,
    const float* __restrict__ b1, const float* __restrict__ W2,
    const float* __restrict__ b2, unsigned* __restrict__ gf, int N, int CPW) {
  __shared__ __align__(16) _Float16 w2f[8192];  // [kc=8][j2=128][e=8] blocked
  __shared__ __align__(16) _Float16 w1e[1024];  // [kc=2][j=64][e=8]: k'=0-6 W1h,7-13 W1h(xl),14 b1h,15 b1l

  const int t = threadIdx.x;
  const int w = t >> 6;
  const int lane = t & 63;
  const int col = lane & 31;
  const int kh2 = lane >> 5;

  // ---- one-time weight staging ----
  {
    const int j = t & 127, kh = t >> 7;
    for (int kk = 0; kk < 32; ++kk) {
      const int k = kh * 32 + kk;
      w2f[((k >> 3) * 128 + j) * 8 + (k & 7)] = (_Float16)W2[k * 128 + j];
    }
  }
  if (t < 128) {
    const int j = t & 63, kc = t >> 6;
    for (int e = 0; e < 8; ++e) {
      const int kp = kc * 8 + e;
      float val;
      if (kp < 7)       val = W1[kp * 64 + j];
      else if (kp < 14) val = W1[(kp - 7) * 64 + j];
      else if (kp == 14) val = b1[j];
      else { const float b = b1[j]; val = b - (float)(_Float16)b; }
      w1e[(kc * 64 + j) * 8 + e] = (_Float16)val;
    }
  }
  __syncthreads();

  float b2v[4];
  #pragma unroll
  for (int jt = 0; jt < 4; ++jt) b2v[jt] = b2[jt * 32 + col];
  f32x16 zf;
  #pragma unroll
  for (int e = 0; e < 16; ++e) zf[e] = 0.0f;

  // ---- chunk setup ----
  const int gwave = blockIdx.x * 4 + w;
  const int start = gwave * CPW;
  if (start >= N) return;
  const int end = min(start + CPW, N);
  const int prevb = (start == 0) ? -1 : bidx[start - 1];
  const int nextb = (end >= N) ? -1 : bidx[end];
  int run_b = bidx[start];
  float run_s[4];
  #pragma unroll
  for (int jt = 0; jt < 4; ++jt) run_s[jt] = -3.0e38f;

  auto FLUSH = [&](int b, const float* m) {
    const bool interior = (b != prevb) && (b != nextb);
    if (lane < 32) {
      #pragma unroll
      for (int jt = 0; jt < 4; ++jt) {
        if (m[jt] > -2.9e38f) {
          const unsigned enc = f2mono(lrelu(m[jt] + b2v[jt]));
          unsigned* addr = &gf[b * 128 + jt * 32 + col];
          if (interior) *addr = enc; else atomicMax(addr, enc);
        }
      }
    }
  };

  for (int pbase = start; pbase < end; pbase += 32) {
    const int pc = min(pbase + col, N - 1);
    const int bi = bidx[pc];

    // ---- load inputs + fp16 2-term decompose of x ----
    float in[7];
    in[0] = muons[pc * 3 + 0];
    in[1] = muons[pc * 3 + 1];
    in[2] = muons[pc * 3 + 2];
    const f32x4 c4 = *(const f32x4*)&cond[bi * 4];
    in[3] = c4.x; in[4] = c4.y; in[5] = c4.z; in[6] = c4.w;

    const unsigned pA0 = pkrtz(in[0], in[1]);
    const unsigned pA1 = pkrtz(in[2], in[3]);
    const unsigned pA2 = pkrtz(in[4], in[5]);
    const half2v hA0 = __builtin_bit_cast(half2v, pA0);
    const half2v hA1 = __builtin_bit_cast(half2v, pA1);
    const half2v hA2 = __builtin_bit_cast(half2v, pA2);
    const float xl0 = in[0] - (float)hA0[0];
    const unsigned pA3 = pkrtz(in[6], xl0);          // (xh6, xl0)
    const half2v hA3 = __builtin_bit_cast(half2v, pA3);
    const float xl1 = in[1] - (float)hA0[1];
    const float xl2 = in[2] - (float)hA1[0];
    const float xl3 = in[3] - (float)hA1[1];
    const float xl4 = in[4] - (float)hA2[0];
    const float xl5 = in[5] - (float)hA2[1];
    const float xl6 = in[6] - (float)hA3[0];
    const unsigned pB0 = pkrtz(xl1, xl2);
    const unsigned pB1 = pkrtz(xl3, xl4);
    const unsigned pB2 = pkrtz(xl5, xl6);
    const unsigned pB3 = 0x3C003C00u;                // (1.0, 1.0) -> bias slots
    u32x4 bu;
    bu[0] = kh2 ? pB0 : pA0;
    bu[1] = kh2 ? pB1 : pA1;
    bu[2] = kh2 ? pB2 : pA2;
    bu[3] = kh2 ? pB3 : pA3;
    const half8 bfr = ash8(bu);

    // ---- layer1: D1[j 0..63][p], bias folded; 2 MFMAs ----
    const half8 a1lo = *(const half8*)&w1e[(kh2 * 64 + col) * 8];
    const half8 a1hi = *(const half8*)&w1e[(kh2 * 64 + 32 + col) * 8];
    const f32x16 acc0 = __builtin_amdgcn_mfma_f32_32x32x16_f16(a1lo, bfr, zf, 0, 0, 0);
    const f32x16 acc1 = __builtin_amdgcn_mfma_f32_32x32x16_f16(a1hi, bfr, zf, 0, 0, 0);

    // ---- lrelu + fp16 pack: pk0/pk1 slots 2q+{0,1} = j pairs (8q+4*kh2 +{0,1},{2,3}) ----
    unsigned pk0[8], pk1[8];
    #pragma unroll
    for (int q = 0; q < 4; ++q) {
      pk0[2 * q]     = pkrtz(lrelu(acc0[4 * q]),     lrelu(acc0[4 * q + 1]));
      pk0[2 * q + 1] = pkrtz(lrelu(acc0[4 * q + 2]), lrelu(acc0[4 * q + 3]));
      pk1[2 * q]     = pkrtz(lrelu(acc1[4 * q]),     lrelu(acc1[4 * q + 1]));
      pk1[2 * q + 1] = pkrtz(lrelu(acc1[4 * q + 2]), lrelu(acc1[4 * q + 3]));
    }

    // ---- layer2: A-frag via half-wave exchange; 16 MFMAs ----
    f32x16 acc2[4];
    #pragma unroll
    for (int ks = 0; ks < 4; ++ks) {
      const unsigned* s = (ks < 2) ? pk0 : pk1;
      const int base = (ks & 1) * 4;
      const unsigned send0 = kh2 ? s[base + 0] : s[base + 2];
      const unsigned send1 = kh2 ? s[base + 1] : s[base + 3];
      const unsigned recv0 = (unsigned)__shfl_xor((int)send0, 32);
      const unsigned recv1 = (unsigned)__shfl_xor((int)send1, 32);
      u32x4 au;
      au[0] = kh2 ? recv0 : s[base + 0];
      au[1] = kh2 ? recv1 : s[base + 1];
      au[2] = kh2 ? s[base + 2] : recv0;
      au[3] = kh2 ? s[base + 3] : recv1;
      const half8 A = ash8(au);
      const int kcb = (2 * ks + kh2) * 128;
      #pragma unroll
      for (int jt = 0; jt < 4; ++jt) {
        const half8 B = *(const half8*)&w2f[(kcb + jt * 32 + col) * 8];
        acc2[jt] = __builtin_amdgcn_mfma_f32_32x32x16_f16(A, B, (ks == 0) ? zf : acc2[jt], 0, 0, 0);
      }
    }

    // ---- running segmented max (bias+lrelu deferred to flush) ----
    const int bA = __shfl(bi, 0);
    const int bB = __shfl(bi, 31);
    if (bA != run_b) {
      FLUSH(run_b, run_s);
      #pragma unroll
      for (int jt = 0; jt < 4; ++jt) run_s[jt] = -3.0e38f;
      run_b = bA;
    }
    if (bA == bB) {
      #pragma unroll
      for (int jt = 0; jt < 4; ++jt) {
        const f32x16 a = acc2[jt];
        float m = fmaxf(fmaxf(fmaxf(a[0], a[1]), fmaxf(a[2], a[3])),
                        fmaxf(fmaxf(a[4], a[5]), fmaxf(a[6], a[7])));
        const float m2 = fmaxf(fmaxf(fmaxf(a[8], a[9]), fmaxf(a[10], a[11])),
                               fmaxf(fmaxf(a[12], a[13]), fmaxf(a[14], a[15])));
        m = fmaxf(m, m2);
        m = fmaxf(m, __shfl_xor(m, 32));
        run_s[jt] = fmaxf(run_s[jt], m);
      }
    } else {
      int pbi[16];
      #pragma unroll
      for (int r = 0; r < 16; ++r) {
        const int rr = (r & 3) + ((r >> 2) << 3) + (kh2 << 2);
        pbi[r] = __shfl(bi, rr);
      }
      for (int b = bA; b <= bB; ++b) {
        float m[4];
        #pragma unroll
        for (int jt = 0; jt < 4; ++jt) {
          float mm = -3.0e38f;
          #pragma unroll
          for (int r = 0; r < 16; ++r)
            if (pbi[r] == b) mm = fmaxf(mm, acc2[jt][r]);
          mm = fmaxf(mm, __shfl_xor(mm, 32));
          if (b == bA) mm = fmaxf(mm, run_s[jt]);
          m[jt] = mm;
        }
        if (b < bB) {
          FLUSH(b, m);
        } else {
          #pragma unroll
          for (int jt = 0; jt < 4; ++jt) run_s[jt] = m[jt];
        }
      }
      run_b = bB;
    }
  }
  FLUSH(run_b, run_s);
}

// ---------------- decision MLP: [B,132] @ W3 -> lrelu -> @ W4 + b4 ----------------
__global__ __launch_bounds__(128) void sc_final(
    const unsigned* __restrict__ gf, const float* __restrict__ cond,
    const float* __restrict__ W3, const float* __restrict__ b3,
    const float* __restrict__ W4, const float* __restrict__ b4,
    float* __restrict__ out, int B) {
  __shared__ __align__(16) float w3t[128 * 132];  // [j][k]
  __shared__ float b3s[128], w4s[128];
  __shared__ __align__(16) float din[8 * 132];
  __shared__ float wred[16];
  const int t = threadIdx.x;
  for (int k = 0; k < 132; ++k) w3t[t * 132 + k] = W3[k * 128 + t];
  b3s[t] = b3[t];
  w4s[t] = W4[t];
  __syncthreads();

  const int nocts = (B + 7) >> 3;
  for (int oc = blockIdx.x; oc < nocts; oc += gridDim.x) {
    const int rbase = oc << 3;
    #pragma unroll
    for (int r = 0; r < 8; ++r) {
      const int row = rbase + r;
      if (row < B) {
        din[r * 132 + t] = mono2f(gf[row * 128 + t]);
        if (t < 4) din[r * 132 + 128 + t] = cond[row * 4 + t];
      }
    }
    __syncthreads();
    float a8[8];
    #pragma unroll
    for (int r = 0; r < 8; ++r) a8[r] = b3s[t];
    for (int kg = 0; kg < 33; ++kg) {
      const f32x4 wv = *(const f32x4*)&w3t[t * 132 + kg * 4];
      #pragma unroll
      for (int r = 0; r < 8; ++r) {
        const f32x4 dv = *(const f32x4*)&din[r * 132 + kg * 4];
        a8[r] += wv[0] * dv[0] + wv[1] * dv[1] + wv[2] * dv[2] + wv[3] * dv[3];
      }
    }
    const float w4v = w4s[t];
    #pragma unroll
    for (int r = 0; r < 8; ++r) a8[r] = lrelu(a8[r]) * w4v;
    const int lane = t & 63;
    const int wv_ = t >> 6;
    #pragma unroll
    for (int r = 0; r < 8; ++r) {
      float s = a8[r];
      s += __shfl_xor(s, 1);  s += __shfl_xor(s, 2);
      s += __shfl_xor(s, 4);  s += __shfl_xor(s, 8);
      s += __shfl_xor(s, 16); s += __shfl_xor(s, 32);
      if (lane == 0) wred[wv_ * 8 + r] = s;
    }
    __syncthreads();
    if (t < 8) {
      const int row = rbase + t;
      if (row < B) out[row] = wred[t] + wred[8 + t] + b4[0];
    }
    __syncthreads();
  }
}

extern "C" void kernel_launch(void* const* d_in, const int* in_sizes, int n_in,
                              void* d_out, int out_size, void* d_ws, size_t ws_size,
                              hipStream_t stream) {
  const float* muons = (const float*)d_in[0];
  const int* bidx = (const int*)d_in[1];
  const float* cond = (const float*)d_in[2];
  const float* W1 = (const float*)d_in[4];
  const float* b1 = (const float*)d_in[5];
  const float* W2 = (const float*)d_in[6];
  const float* b2 = (const float*)d_in[7];
  const float* W3 = (const float*)d_in[8];
  const float* b3 = (const float*)d_in[9];
  const float* W4 = (const float*)d_in[10];
  const float* b4 = (const float*)d_in[11];
  float* out = (float*)d_out;
  const int N = in_sizes[1];
  const int B = out_size;
  unsigned* gf = (unsigned*)d_ws;  // B*128 mono-encoded uints (8 MB)

  const int total4 = (B * 128) / 4;
  sc_init<<<(total4 + 255) / 256, 256, 0, stream>>>(gf, total4);

  const int nblocks = 1024;
  const int nwaves = nblocks * 4;
  const int cpw = (((N + nwaves - 1) / nwaves) + 31) & ~31;  // points per wave, ×32
  sc_main<<<nblocks, 256, 0, stream>>>(muons, bidx, cond, W1, b1, W2, b2, gf, N, cpw);
  sc_final<<<1024, 128, 0, stream>>>(gf, cond, W3, b3, W4, b4, out, B);
  (void)n_in; (void)ws_size;
}

// Round 6
// 177.141 us; speedup vs baseline: 1.7625x; 1.7625x over previous
//
#include <hip/hip_runtime.h>

typedef float f32x4 __attribute__((ext_vector_type(4)));
typedef float f32x16 __attribute__((ext_vector_type(16)));
typedef _Float16 half8 __attribute__((ext_vector_type(8)));
typedef _Float16 half2v __attribute__((ext_vector_type(2)));
typedef unsigned u32x4 __attribute__((ext_vector_type(4)));

__device__ __forceinline__ unsigned f2mono(float f) {
  unsigned u = __float_as_uint(f);
  return (u & 0x80000000u) ? ~u : (u | 0x80000000u);
}
__device__ __forceinline__ float mono2f(unsigned u) {
  return (u & 0x80000000u) ? __uint_as_float(u & 0x7fffffffu) : __uint_as_float(~u);
}
__device__ __forceinline__ float lrelu(float x) { return fmaxf(x, 0.2f * x); }
__device__ __forceinline__ unsigned pkrtz(float a, float b) {
  return __builtin_bit_cast(unsigned, __builtin_amdgcn_cvt_pkrtz(a, b));
}
__device__ __forceinline__ half8 ash8(u32x4 u) { return __builtin_bit_cast(half8, u); }

// ---------------- init: global_feats = mono(-1e9) ----------------
__global__ void sc_init(unsigned* __restrict__ gf, int total4) {
  int i = blockIdx.x * blockDim.x + threadIdx.x;
  if (i < total4) {
    unsigned m = f2mono(-1.0e9f);
    ((uint4*)gf)[i] = make_uint4(m, m, m, m);
  }
}

// ---- fused: gather + L1(fp16 x-split MFMA) + L2(fp16 MFMA) + running seg-max ----
// Wave owns one contiguous chunk. Running per-feature max in regs; flush on batch
// transition. Interior batches -> plain store; boundary -> atomicMax.
// __launch_bounds__(256,2): pins VGPR cap at 128 — the validated no-spill point
// (R4). Compiler default (R5) picks 64 => 860 MB scratch traffic; (256,4) (R3)
// picks 64 too => 2.3 GB. Do not remove.
__global__ __launch_bounds__(256, 2) void sc_main(
    const float* __restrict__ muons, const int* __restrict__ bidx,
    const float* __restrict__ cond, const float* __restrict__ W1,
    const float* __restrict__ b1, const float* __restrict__ W2,
    const float* __restrict__ b2, unsigned* __restrict__ gf, int N, int CPW) {
  __shared__ __align__(16) _Float16 w2f[8192];  // [kc=8][j2=128][e=8] blocked
  __shared__ __align__(16) _Float16 w1e[1024];  // [kc=2][j=64][e=8]: k'=0-6 W1h,7-13 W1h(xl),14 b1h,15 b1l

  const int t = threadIdx.x;
  const int w = t >> 6;
  const int lane = t & 63;
  const int col = lane & 31;
  const int kh2 = lane >> 5;

  // ---- one-time weight staging ----
  {
    const int j = t & 127, kh = t >> 7;
    for (int kk = 0; kk < 32; ++kk) {
      const int k = kh * 32 + kk;
      w2f[((k >> 3) * 128 + j) * 8 + (k & 7)] = (_Float16)W2[k * 128 + j];
    }
  }
  if (t < 128) {
    const int j = t & 63, kc = t >> 6;
    for (int e = 0; e < 8; ++e) {
      const int kp = kc * 8 + e;
      float val;
      if (kp < 7)       val = W1[kp * 64 + j];
      else if (kp < 14) val = W1[(kp - 7) * 64 + j];
      else if (kp == 14) val = b1[j];
      else { const float b = b1[j]; val = b - (float)(_Float16)b; }
      w1e[(kc * 64 + j) * 8 + e] = (_Float16)val;
    }
  }
  __syncthreads();

  float b2v[4];
  #pragma unroll
  for (int jt = 0; jt < 4; ++jt) b2v[jt] = b2[jt * 32 + col];
  f32x16 zf;
  #pragma unroll
  for (int e = 0; e < 16; ++e) zf[e] = 0.0f;

  // ---- chunk setup ----
  const int gwave = blockIdx.x * 4 + w;
  const int start = gwave * CPW;
  if (start >= N) return;
  const int end = min(start + CPW, N);
  const int prevb = (start == 0) ? -1 : bidx[start - 1];
  const int nextb = (end >= N) ? -1 : bidx[end];
  int run_b = bidx[start];
  float run_s[4];
  #pragma unroll
  for (int jt = 0; jt < 4; ++jt) run_s[jt] = -3.0e38f;

  auto FLUSH = [&](int b, const float* m) {
    const bool interior = (b != prevb) && (b != nextb);
    if (lane < 32) {
      #pragma unroll
      for (int jt = 0; jt < 4; ++jt) {
        if (m[jt] > -2.9e38f) {
          const unsigned enc = f2mono(lrelu(m[jt] + b2v[jt]));
          unsigned* addr = &gf[b * 128 + jt * 32 + col];
          if (interior) *addr = enc; else atomicMax(addr, enc);
        }
      }
    }
  };

  for (int pbase = start; pbase < end; pbase += 32) {
    const int pc = min(pbase + col, N - 1);
    const int bi = bidx[pc];

    // ---- load inputs + fp16 2-term decompose of x ----
    float in[7];
    in[0] = muons[pc * 3 + 0];
    in[1] = muons[pc * 3 + 1];
    in[2] = muons[pc * 3 + 2];
    const f32x4 c4 = *(const f32x4*)&cond[bi * 4];
    in[3] = c4.x; in[4] = c4.y; in[5] = c4.z; in[6] = c4.w;

    const unsigned pA0 = pkrtz(in[0], in[1]);
    const unsigned pA1 = pkrtz(in[2], in[3]);
    const unsigned pA2 = pkrtz(in[4], in[5]);
    const half2v hA0 = __builtin_bit_cast(half2v, pA0);
    const half2v hA1 = __builtin_bit_cast(half2v, pA1);
    const half2v hA2 = __builtin_bit_cast(half2v, pA2);
    const float xl0 = in[0] - (float)hA0[0];
    const unsigned pA3 = pkrtz(in[6], xl0);          // (xh6, xl0)
    const half2v hA3 = __builtin_bit_cast(half2v, pA3);
    const float xl1 = in[1] - (float)hA0[1];
    const float xl2 = in[2] - (float)hA1[0];
    const float xl3 = in[3] - (float)hA1[1];
    const float xl4 = in[4] - (float)hA2[0];
    const float xl5 = in[5] - (float)hA2[1];
    const float xl6 = in[6] - (float)hA3[0];
    const unsigned pB0 = pkrtz(xl1, xl2);
    const unsigned pB1 = pkrtz(xl3, xl4);
    const unsigned pB2 = pkrtz(xl5, xl6);
    const unsigned pB3 = 0x3C003C00u;                // (1.0, 1.0) -> bias slots
    u32x4 bu;
    bu[0] = kh2 ? pB0 : pA0;
    bu[1] = kh2 ? pB1 : pA1;
    bu[2] = kh2 ? pB2 : pA2;
    bu[3] = kh2 ? pB3 : pA3;
    const half8 bfr = ash8(bu);

    // ---- layer1: D1[j 0..63][p], bias folded; 2 MFMAs ----
    const half8 a1lo = *(const half8*)&w1e[(kh2 * 64 + col) * 8];
    const half8 a1hi = *(const half8*)&w1e[(kh2 * 64 + 32 + col) * 8];
    const f32x16 acc0 = __builtin_amdgcn_mfma_f32_32x32x16_f16(a1lo, bfr, zf, 0, 0, 0);
    const f32x16 acc1 = __builtin_amdgcn_mfma_f32_32x32x16_f16(a1hi, bfr, zf, 0, 0, 0);

    // ---- lrelu + fp16 pack: pk0/pk1 slots 2q+{0,1} = j pairs (8q+4*kh2 +{0,1},{2,3}) ----
    unsigned pk0[8], pk1[8];
    #pragma unroll
    for (int q = 0; q < 4; ++q) {
      pk0[2 * q]     = pkrtz(lrelu(acc0[4 * q]),     lrelu(acc0[4 * q + 1]));
      pk0[2 * q + 1] = pkrtz(lrelu(acc0[4 * q + 2]), lrelu(acc0[4 * q + 3]));
      pk1[2 * q]     = pkrtz(lrelu(acc1[4 * q]),     lrelu(acc1[4 * q + 1]));
      pk1[2 * q + 1] = pkrtz(lrelu(acc1[4 * q + 2]), lrelu(acc1[4 * q + 3]));
    }

    // ---- layer2: A-frag via half-wave exchange; 16 MFMAs ----
    f32x16 acc2[4];
    #pragma unroll
    for (int ks = 0; ks < 4; ++ks) {
      const unsigned* s = (ks < 2) ? pk0 : pk1;
      const int base = (ks & 1) * 4;
      const unsigned send0 = kh2 ? s[base + 0] : s[base + 2];
      const unsigned send1 = kh2 ? s[base + 1] : s[base + 3];
      const unsigned recv0 = (unsigned)__shfl_xor((int)send0, 32);
      const unsigned recv1 = (unsigned)__shfl_xor((int)send1, 32);
      u32x4 au;
      au[0] = kh2 ? recv0 : s[base + 0];
      au[1] = kh2 ? recv1 : s[base + 1];
      au[2] = kh2 ? s[base + 2] : recv0;
      au[3] = kh2 ? s[base + 3] : recv1;
      const half8 A = ash8(au);
      const int kcb = (2 * ks + kh2) * 128;
      #pragma unroll
      for (int jt = 0; jt < 4; ++jt) {
        const half8 B = *(const half8*)&w2f[(kcb + jt * 32 + col) * 8];
        acc2[jt] = __builtin_amdgcn_mfma_f32_32x32x16_f16(A, B, (ks == 0) ? zf : acc2[jt], 0, 0, 0);
      }
    }

    // ---- running segmented max (bias+lrelu deferred to flush) ----
    const int bA = __shfl(bi, 0);
    const int bB = __shfl(bi, 31);
    if (bA != run_b) {
      FLUSH(run_b, run_s);
      #pragma unroll
      for (int jt = 0; jt < 4; ++jt) run_s[jt] = -3.0e38f;
      run_b = bA;
    }
    if (bA == bB) {
      #pragma unroll
      for (int jt = 0; jt < 4; ++jt) {
        const f32x16 a = acc2[jt];
        float m = fmaxf(fmaxf(fmaxf(a[0], a[1]), fmaxf(a[2], a[3])),
                        fmaxf(fmaxf(a[4], a[5]), fmaxf(a[6], a[7])));
        const float m2 = fmaxf(fmaxf(fmaxf(a[8], a[9]), fmaxf(a[10], a[11])),
                               fmaxf(fmaxf(a[12], a[13]), fmaxf(a[14], a[15])));
        m = fmaxf(m, m2);
        m = fmaxf(m, __shfl_xor(m, 32));
        run_s[jt] = fmaxf(run_s[jt], m);
      }
    } else {
      int pbi[16];
      #pragma unroll
      for (int r = 0; r < 16; ++r) {
        const int rr = (r & 3) + ((r >> 2) << 3) + (kh2 << 2);
        pbi[r] = __shfl(bi, rr);
      }
      for (int b = bA; b <= bB; ++b) {
        float m[4];
        #pragma unroll
        for (int jt = 0; jt < 4; ++jt) {
          float mm = -3.0e38f;
          #pragma unroll
          for (int r = 0; r < 16; ++r)
            if (pbi[r] == b) mm = fmaxf(mm, acc2[jt][r]);
          mm = fmaxf(mm, __shfl_xor(mm, 32));
          if (b == bA) mm = fmaxf(mm, run_s[jt]);
          m[jt] = mm;
        }
        if (b < bB) {
          FLUSH(b, m);
        } else {
          #pragma unroll
          for (int jt = 0; jt < 4; ++jt) run_s[jt] = m[jt];
        }
      }
      run_b = bB;
    }
  }
  FLUSH(run_b, run_s);
}

// ---------------- decision MLP: [B,132] @ W3 -> lrelu -> @ W4 + b4 ----------------
__global__ __launch_bounds__(128) void sc_final(
    const unsigned* __restrict__ gf, const float* __restrict__ cond,
    const float* __restrict__ W3, const float* __restrict__ b3,
    const float* __restrict__ W4, const float* __restrict__ b4,
    float* __restrict__ out, int B) {
  __shared__ __align__(16) float w3t[128 * 132];  // [j][k]
  __shared__ float b3s[128], w4s[128];
  __shared__ __align__(16) float din[8 * 132];
  __shared__ float wred[16];
  const int t = threadIdx.x;
  for (int k = 0; k < 132; ++k) w3t[t * 132 + k] = W3[k * 128 + t];
  b3s[t] = b3[t];
  w4s[t] = W4[t];
  __syncthreads();

  const int nocts = (B + 7) >> 3;
  for (int oc = blockIdx.x; oc < nocts; oc += gridDim.x) {
    const int rbase = oc << 3;
    #pragma unroll
    for (int r = 0; r < 8; ++r) {
      const int row = rbase + r;
      if (row < B) {
        din[r * 132 + t] = mono2f(gf[row * 128 + t]);
        if (t < 4) din[r * 132 + 128 + t] = cond[row * 4 + t];
      }
    }
    __syncthreads();
    float a8[8];
    #pragma unroll
    for (int r = 0; r < 8; ++r) a8[r] = b3s[t];
    for (int kg = 0; kg < 33; ++kg) {
      const f32x4 wv = *(const f32x4*)&w3t[t * 132 + kg * 4];
      #pragma unroll
      for (int r = 0; r < 8; ++r) {
        const f32x4 dv = *(const f32x4*)&din[r * 132 + kg * 4];
        a8[r] += wv[0] * dv[0] + wv[1] * dv[1] + wv[2] * dv[2] + wv[3] * dv[3];
      }
    }
    const float w4v = w4s[t];
    #pragma unroll
    for (int r = 0; r < 8; ++r) a8[r] = lrelu(a8[r]) * w4v;
    const int lane = t & 63;
    const int wv_ = t >> 6;
    #pragma unroll
    for (int r = 0; r < 8; ++r) {
      float s = a8[r];
      s += __shfl_xor(s, 1);  s += __shfl_xor(s, 2);
      s += __shfl_xor(s, 4);  s += __shfl_xor(s, 8);
      s += __shfl_xor(s, 16); s += __shfl_xor(s, 32);
      if (lane == 0) wred[wv_ * 8 + r] = s;
    }
    __syncthreads();
    if (t < 8) {
      const int row = rbase + t;
      if (row < B) out[row] = wred[t] + wred[8 + t] + b4[0];
    }
    __syncthreads();
  }
}

extern "C" void kernel_launch(void* const* d_in, const int* in_sizes, int n_in,
                              void* d_out, int out_size, void* d_ws, size_t ws_size,
                              hipStream_t stream) {
  const float* muons = (const float*)d_in[0];
  const int* bidx = (const int*)d_in[1];
  const float* cond = (const float*)d_in[2];
  const float* W1 = (const float*)d_in[4];
  const float* b1 = (const float*)d_in[5];
  const float* W2 = (const float*)d_in[6];
  const float* b2 = (const float*)d_in[7];
  const float* W3 = (const float*)d_in[8];
  const float* b3 = (const float*)d_in[9];
  const float* W4 = (const float*)d_in[10];
  const float* b4 = (const float*)d_in[11];
  float* out = (float*)d_out;
  const int N = in_sizes[1];
  const int B = out_size;
  unsigned* gf = (unsigned*)d_ws;  // B*128 mono-encoded uints (8 MB)

  const int total4 = (B * 128) / 4;
  sc_init<<<(total4 + 255) / 256, 256, 0, stream>>>(gf, total4);

  const int nblocks = 1024;
  const int nwaves = nblocks * 4;
  const int cpw = (((N + nwaves - 1) / nwaves) + 31) & ~31;  // points per wave, ×32
  sc_main<<<nblocks, 256, 0, stream>>>(muons, bidx, cond, W1, b1, W2, b2, gf, N, cpw);
  sc_final<<<1024, 128, 0, stream>>>(gf, cond, W3, b3, W4, b4, out, B);
  (void)n_in; (void)ws_size;
}